// Round 6
// baseline (320.738 us; speedup 1.0000x reference)
//
#include <hip/hip_runtime.h>
#include <math.h>

#define N_NODES 512
#define DIM 128
#define NANCH 192
#define G3 384           // 3*DIM gate width
#define FOUT 47
#define DBINS 21
#define WPAD 132         // padded row stride (33 float4s) -> conflict-free ds_read_b128

__device__ __forceinline__ float fast_sigmoid(float x) {
    return __builtin_amdgcn_rcpf(1.f + __expf(-x));
}
__device__ __forceinline__ float fast_tanh(float x) {
    return 1.f - 2.f * __builtin_amdgcn_rcpf(1.f + __expf(2.f * x));
}

// ============ Kernel 1: fused [xW GEMM | membership + abnormal + H=1 BiGRU] ============
// (byte-identical to R8)
__global__ __launch_bounds__(384) void prep_kernel(
    const float* __restrict__ emb, const float* __restrict__ tpin,
    const float* __restrict__ Wih, const float* __restrict__ bih,
    const float* __restrict__ alp, const float* __restrict__ anchors,
    const float* __restrict__ npred, const float* __restrict__ skern,
    const float* __restrict__ aWih, const float* __restrict__ aWhh,
    const float* __restrict__ abih, const float* __restrict__ abhh,
    float* __restrict__ xW, int* __restrict__ members,
    int* __restrict__ lens, float* __restrict__ abn_res)
{
    int blk = blockIdx.x;
    int tid = threadIdx.x;     // 0..383
    if (blk < 192) {
        int sd = blk >> 5;         // 0..5
        int ng = blk & 31;         // 0..31
        __shared__ __align__(16) float xs[16][DIM];
        for (int idx = tid; idx < 16 * DIM; idx += 384) {
            int m = idx >> 7, k = idx & 127;
            int node = ng * 16 + m;
            float tv = tpin[node];
            float freq = 10.f * (float)k / 127.f;
            xs[m][k] = emb[node * DIM + k] + 0.05f * __sinf(tv * freq);
        }
        __syncthreads();
        float acc[16];
        float b = bih[sd * G3 + tid];
        #pragma unroll
        for (int m = 0; m < 16; ++m) acc[m] = b;
        const float* wrow = Wih + ((size_t)sd * G3 + tid) * DIM;
        for (int k = 0; k < DIM; k += 4) {
            float4 w4 = *(const float4*)(wrow + k);
            #pragma unroll
            for (int m = 0; m < 16; ++m) {
                float4 xv = *(const float4*)&xs[m][k];   // wave-uniform b128 broadcast
                acc[m] = fmaf(w4.x, xv.x, acc[m]);
                acc[m] = fmaf(w4.y, xv.y, acc[m]);
                acc[m] = fmaf(w4.z, xv.z, acc[m]);
                acc[m] = fmaf(w4.w, xv.w, acc[m]);
            }
        }
        #pragma unroll
        for (int m = 0; m < 16; ++m)
            xW[((size_t)sd * N_NODES + ng * 16 + m) * G3 + tid] = acc[m];
    } else {
        int a = blk - 192;
        float al = alp[0];
        float s0 = anchors[a * 2 + 0];
        float e0 = anchors[a * 2 + 1];
        __shared__ int memloc[N_NODES];
        __shared__ float abn_lds[N_NODES];
        for (int node = tid; node < N_NODES; node += 384) {
            float sc[5];
            #pragma unroll
            for (int ch = 0; ch < 5; ++ch) {
                float acc = 0.f;
                #pragma unroll
                for (int k = 0; k < 5; ++k) {
                    int r = node + k - 2;
                    if (r >= 0 && r < N_NODES) acc += skern[k] * npred[r * 5 + ch];
                }
                sc[ch] = acc;
            }
            float m = sc[0];
            #pragma unroll
            for (int ch = 1; ch < 5; ++ch) m = fmaxf(m, sc[ch]);
            float sum = 0.f;
            #pragma unroll
            for (int ch = 0; ch < 5; ++ch) sum += __expf(sc[ch] - m);
            abn_lds[node] = __expf(sc[0] - m) / sum;
        }
        __syncthreads();
        if (tid < 64) {
            int lane = tid;
            int count = 0;
            for (int c = 0; c < N_NODES / 64; ++c) {
                int node = c * 64 + lane;
                float tp = tpin[node] * al;
                bool in = (tp >= s0) && (tp <= e0);
                unsigned long long m = __ballot(in);
                if (in) {
                    int pos = count + __popcll(m & ((1ull << lane) - 1ull));
                    members[a * N_NODES + pos] = node;
                    memloc[pos] = node;
                }
                count += __popcll(m);
            }
            if (lane == 0) lens[a] = count;
            int sc3 = a >> 6;
            float h = 0.f;
            if (lane < 2) {
                int sd = sc3 * 2 + lane;
                float wi0 = aWih[sd*3+0], wi1 = aWih[sd*3+1], wi2 = aWih[sd*3+2];
                float wh0 = aWhh[sd*3+0], wh1 = aWhh[sd*3+1], wh2 = aWhh[sd*3+2];
                float bi0 = abih[sd*3+0], bi1 = abih[sd*3+1], bi2 = abih[sd*3+2];
                float bh0 = abhh[sd*3+0], bh1 = abhh[sd*3+1], bh2 = abhh[sd*3+2];
                for (int t = 0; t < count; ++t) {
                    int idx = lane ? (count - 1 - t) : t;
                    float xv = abn_lds[memloc[idx]];
                    float r = fast_sigmoid(fmaf(wi0, xv, bi0) + fmaf(wh0, h, bh0));
                    float z = fast_sigmoid(fmaf(wi1, xv, bi1) + fmaf(wh1, h, bh1));
                    float nv = fast_tanh(fmaf(wi2, xv, bi2) + r * fmaf(wh2, h, bh2));
                    h = (1.f - z) * nv + z * h;
                }
            }
            float hb = __shfl(h, 1);
            if (lane == 0) abn_res[a] = 0.5f * (h + hb);
        }
    }
}

// ============ Kernel 2: H=128 GRU — R14: LDS-resident wr/wz + wn stream + anchor pairing ====
// R9-R13 arc: the register allocator refuses to keep ~100 loop-crossing weights in VGPRs
// (spills to scratch in every config; best 88/96 kept). RA-proof redesign:
//  - wr,wz gates (128 KB fp32) live in LDS (cannot be spilled); row stride WPAD=132
//    floats makes the per-step ds_read_b128 pattern conflict-free ((j+q)&7 uniform).
//  - wn gate (64 KB) streams from L2 each step — but each block now serves TWO anchors
//    of the same (scale,dir), so all weight traffic is amortized 2x. 192 blocks,
//    137 KB LDS -> 1 block/CU, ALL blocks resident from t=0 (no placement tricks).
//    L2 demand: 24 blk/XCD * 64 KB / ~460ns ~= 3.3 TB/s < 4.3 TB/s cap (first feasible).
//  - pairing: within each scale, anchors sorted by width; pair = (2k, 2k+1) longest ->
//    intra-pair len mismatch minimized. Each anchor keeps its own h/gi/members; after
//    its len, h copies through (exact).
// All live ranges loop-local -> nothing for the RA to spill.
__global__ __launch_bounds__(512) void gru_feat_kernel(
    const float* __restrict__ xW, const float* __restrict__ Whh,
    const float* __restrict__ bhh, const int* __restrict__ members,
    const int* __restrict__ lens, const float* __restrict__ anchors,
    float* __restrict__ feat_out)
{
    int bb = blockIdx.x;       // 0..191
    int t0 = threadIdx.x;      // 0..511
    int j  = t0 >> 2;          // 0..127 : owned h element
    int s  = t0 & 3;           // 0..3   : 32-wide K slice
    int sc  = bb >> 6;         // scale 0..2 (64 blocks per scale)
    int idx = bb & 63;
    int dir = idx & 1;
    int pr  = idx >> 1;        // pair rank 0..31
    int sd  = sc * 2 + dir;

    __shared__ __align__(16) float ldsW[2 * DIM * WPAD];   // wr rows 0..127, wz rows 128..255
    __shared__ __align__(16) float hbA[2][4][36];
    __shared__ __align__(16) float hbB[2][4][36];
    __shared__ int perm_l[64];

    // ---- rank this scale's 64 anchors by width desc (bijective) ----
    if (t0 < 64) {
        int aa = sc * 64 + t0;
        float w = anchors[2 * aa + 1] - anchors[2 * aa];
        int rank = 0;
        for (int q = 0; q < 64; ++q) {
            int aq = sc * 64 + q;
            float wq = anchors[2 * aq + 1] - anchors[2 * aq];
            rank += (wq > w) || (wq == w && q < t0);
        }
        perm_l[rank] = aa;
    }
    // ---- stage wr,wz into LDS (coalesced float4, padded rows) ----
    const float* wbase = Whh + (size_t)sd * G3 * DIM;
    for (int i = t0; i < 2 * DIM * 32; i += 512) {      // 8192 float4s
        int row = i >> 5, c = (i & 31) << 2;
        *(float4*)&ldsW[row * WPAD + c] = *(const float4*)(wbase + row * DIM + c);
    }
    for (int i = t0; i < 2 * 4 * 36; i += 512) { ((float*)hbA)[i] = 0.f; ((float*)hbB)[i] = 0.f; }
    __syncthreads();

    int a0 = perm_l[2 * pr], a1 = perm_l[2 * pr + 1];

    float bhr = bhh[sd * G3 + j];
    float bhz = bhh[sd * G3 + DIM + j];
    float bhn = bhh[sd * G3 + 2 * DIM + j];

    const float* xWp = xW + (size_t)sd * N_NODES * G3;
    const int* memA = members + a0 * N_NODES;  int lenA = lens[a0];
    const int* memB = members + a1 * N_NODES;  int lenB = lens[a1];
    int T = lenA > lenB ? lenA : lenB;

    // step-0 gi prefetch per anchor
    int n0A = (lenA > 0) ? memA[dir ? (lenA - 1) : 0] : 0;
    float grA = xWp[(size_t)n0A * G3 + j];
    float gzA = xWp[(size_t)n0A * G3 + DIM + j];
    float gnA = xWp[(size_t)n0A * G3 + 2 * DIM + j];
    int n0B = (lenB > 0) ? memB[dir ? (lenB - 1) : 0] : 0;
    float grB = xWp[(size_t)n0B * G3 + j];
    float gzB = xWp[(size_t)n0B * G3 + DIM + j];
    float gnB = xWp[(size_t)n0B * G3 + 2 * DIM + j];

    const float4* wr4 = (const float4*)&ldsW[(size_t)j * WPAD + s * 32];
    const float4* wz4 = (const float4*)&ldsW[(size_t)(DIM + j) * WPAD + s * 32];
    const float4* wnp = (const float4*)(wbase + (size_t)(2 * DIM + j) * DIM + s * 32);

    int cur = 0;
    for (int t = 0; t < T; ++t) {
        // wn stream for this step (8 dwordx4 from L2; issued first, consumed last)
        float4 wnv[8];
        #pragma unroll
        for (int q = 0; q < 8; ++q) wnv[q] = wnp[q];
        // next-step gi prefetch (overlaps compute + barrier)
        float grA_n = 0.f, gzA_n = 0.f, gnA_n = 0.f;
        float grB_n = 0.f, gzB_n = 0.f, gnB_n = 0.f;
        if (t + 1 < lenA) {
            int nn = memA[dir ? (lenA - 2 - t) : (t + 1)];
            grA_n = xWp[(size_t)nn * G3 + j];
            gzA_n = xWp[(size_t)nn * G3 + DIM + j];
            gnA_n = xWp[(size_t)nn * G3 + 2 * DIM + j];
        }
        if (t + 1 < lenB) {
            int nn = memB[dir ? (lenB - 2 - t) : (t + 1)];
            grB_n = xWp[(size_t)nn * G3 + j];
            gzB_n = xWp[(size_t)nn * G3 + DIM + j];
            gnB_n = xWp[(size_t)nn * G3 + 2 * DIM + j];
        }
        // partial dots: weights (LDS + streamed regs) x h (LDS broadcast), both anchors
        float arA = 0.f, azA = 0.f, anA = 0.f, arB = 0.f, azB = 0.f, anB = 0.f;
        const float4* hA4 = (const float4*)&hbA[cur][s][0];
        const float4* hB4 = (const float4*)&hbB[cur][s][0];
        #pragma unroll
        for (int q = 0; q < 8; ++q) {
            float4 wv = wr4[q], zv = wz4[q], nv = wnv[q];
            float4 ha = hA4[q], hb = hB4[q];
            arA = fmaf(wv.x, ha.x, arA); arA = fmaf(wv.y, ha.y, arA);
            arA = fmaf(wv.z, ha.z, arA); arA = fmaf(wv.w, ha.w, arA);
            azA = fmaf(zv.x, ha.x, azA); azA = fmaf(zv.y, ha.y, azA);
            azA = fmaf(zv.z, ha.z, azA); azA = fmaf(zv.w, ha.w, azA);
            anA = fmaf(nv.x, ha.x, anA); anA = fmaf(nv.y, ha.y, anA);
            anA = fmaf(nv.z, ha.z, anA); anA = fmaf(nv.w, ha.w, anA);
            arB = fmaf(wv.x, hb.x, arB); arB = fmaf(wv.y, hb.y, arB);
            arB = fmaf(wv.z, hb.z, arB); arB = fmaf(wv.w, hb.w, arB);
            azB = fmaf(zv.x, hb.x, azB); azB = fmaf(zv.y, hb.y, azB);
            azB = fmaf(zv.z, hb.z, azB); azB = fmaf(zv.w, hb.w, azB);
            anB = fmaf(nv.x, hb.x, anB); anB = fmaf(nv.y, hb.y, anB);
            anB = fmaf(nv.z, hb.z, anB); anB = fmaf(nv.w, hb.w, anB);
        }
        // quad reduction (lanes 4j..4j+3 adjacent in wave)
        arA += __shfl_xor(arA, 1); arA += __shfl_xor(arA, 2);
        azA += __shfl_xor(azA, 1); azA += __shfl_xor(azA, 2);
        anA += __shfl_xor(anA, 1); anA += __shfl_xor(anA, 2);
        arB += __shfl_xor(arB, 1); arB += __shfl_xor(arB, 2);
        azB += __shfl_xor(azB, 1); azB += __shfl_xor(azB, 2);
        anB += __shfl_xor(anB, 1); anB += __shfl_xor(anB, 2);

        float rA = fast_sigmoid(grA + arA + bhr);
        float zA = fast_sigmoid(gzA + azA + bhz);
        float nA = fast_tanh(gnA + rA * (anA + bhn));
        float hjA = hbA[cur][j >> 5][j & 31];
        float hnA = (t < lenA) ? ((1.f - zA) * nA + zA * hjA) : hjA;  // copy-through after lenA

        float rB = fast_sigmoid(grB + arB + bhr);
        float zB = fast_sigmoid(gzB + azB + bhz);
        float nB = fast_tanh(gnB + rB * (anB + bhn));
        float hjB = hbB[cur][j >> 5][j & 31];
        float hnB = (t < lenB) ? ((1.f - zB) * nB + zB * hjB) : hjB;

        if (s == 0) {
            hbA[cur ^ 1][j >> 5][j & 31] = hnA;
            hbB[cur ^ 1][j >> 5][j & 31] = hnB;
        }
        __syncthreads();
        cur ^= 1;
        grA = grA_n; gzA = gzA_n; gnA = gnA_n;
        grB = grB_n; gzB = gzB_n; gnB = gnB_n;
    }
    if (s == 0) {
        feat_out[a0 * 256 + dir * DIM + j] = hbA[cur][j >> 5][j & 31];
        feat_out[a1 * 256 + dir * DIM + j] = hbB[cur][j >> 5][j & 31];
    }
}

// ============ Kernel 3: per-anchor MLP head + boundary refinement ============
// (byte-identical to R8)
__global__ __launch_bounds__(256) void head_kernel(
    const float* __restrict__ feat, const float* __restrict__ abn_res,
    const float* __restrict__ anchors, const float* __restrict__ alp,
    const float* __restrict__ W1, const float* __restrict__ b1,
    const float* __restrict__ W2, const float* __restrict__ b2,
    const float* __restrict__ W3, const float* __restrict__ b3,
    const float* __restrict__ sw, const float* __restrict__ ew,
    float* __restrict__ out)
{
    int a = blockIdx.x;
    int tid = threadIdx.x;   // 0..255
    int s = a >> 6;
    __shared__ float sf[260];
    __shared__ float h1[256];
    __shared__ float h2[256];
    __shared__ float o[FOUT];
    float al = alp[0];
    float st = anchors[a * 2 + 0];
    float en = anchors[a * 2 + 1];
    sf[tid] = feat[a * 256 + tid];
    if (tid == 0) {
        sf[256] = abn_res[a];
        sf[257] = (st + en) * 0.5f / al;
        sf[258] = (en - st) / al;
    }
    __syncthreads();

    const float* w1 = W1 + (size_t)s * 259 * 256;
    float acc = b1[s * 256 + tid];
    for (int jj = 0; jj < 259; ++jj) acc = fmaf(sf[jj], w1[jj * 256 + tid], acc);
    h1[tid] = fmaxf(acc, 0.f);
    __syncthreads();

    const float* w2 = W2 + (size_t)s * 256 * 256;
    acc = b2[s * 256 + tid];
    for (int jj = 0; jj < 256; ++jj) acc = fmaf(h1[jj], w2[jj * 256 + tid], acc);
    h2[tid] = fmaxf(acc, 0.f);
    __syncthreads();

    if (tid < FOUT) {
        const float* w3 = W3 + (size_t)s * 256 * FOUT;
        acc = b3[s * FOUT + tid];
        for (int jj = 0; jj < 256; ++jj) acc = fmaf(h2[jj], w3[jj * FOUT + tid], acc);
        o[tid] = acc;
    }
    __syncthreads();

    if (tid < 2) {   // tid 0: start offset, tid 1: end offset
        const float* lw = (tid == 0) ? (sw + s * DBINS) : (ew + s * DBINS);
        const float* sl = o + tid * DBINS;
        float m = sl[0];
        for (int jj = 1; jj < DBINS; ++jj) m = fmaxf(m, sl[jj]);
        float sum = 0.f, dot = 0.f;
        for (int jj = 0; jj < DBINS; ++jj) {
            float e = __expf(sl[jj] - m);
            sum += e;
            dot = fmaf(e, lw[jj], dot);
        }
        float off = dot / sum;
        float base = (tid == 0) ? st : en;
        out[a * 2 + tid] = fminf(fmaxf(base + off, 0.f), al);
    }
    if (tid == 42) out[2 * NANCH + a] = o[42];                           // conf
    if (tid >= 43 && tid < FOUT) out[3 * NANCH + a * 4 + (tid - 43)] = o[tid]; // cls
}

extern "C" void kernel_launch(void* const* d_in, const int* in_sizes, int n_in,
                              void* d_out, int out_size, void* d_ws, size_t ws_size,
                              hipStream_t stream) {
    const float* emb   = (const float*)d_in[0];
    const float* tpin  = (const float*)d_in[1];
    const float* npred = (const float*)d_in[2];
    const float* alp   = (const float*)d_in[3];
    const float* anch  = (const float*)d_in[4];
    const float* skern = (const float*)d_in[5];
    const float* fWih  = (const float*)d_in[6];
    const float* fWhh  = (const float*)d_in[7];
    const float* fbih  = (const float*)d_in[8];
    const float* fbhh  = (const float*)d_in[9];
    const float* aWih  = (const float*)d_in[10];
    const float* aWhh  = (const float*)d_in[11];
    const float* abih  = (const float*)d_in[12];
    const float* abhh  = (const float*)d_in[13];
    const float* sw    = (const float*)d_in[14];
    const float* ew    = (const float*)d_in[15];
    const float* W1    = (const float*)d_in[16];
    const float* b1    = (const float*)d_in[17];
    const float* W2    = (const float*)d_in[18];
    const float* b2    = (const float*)d_in[19];
    const float* W3    = (const float*)d_in[20];
    const float* b3    = (const float*)d_in[21];

    float* ws = (float*)d_ws;
    float* xW       = ws;                      // 6*512*384 = 1179648
    float* abn_res  = ws + 1179648;            // 192 (pad 256)
    float* feat     = ws + 1179904;            // 192*256 = 49152
    int*   members  = (int*)(ws + 1229056);    // 192*512 ints = 98304
    int*   lens     = (int*)(ws + 1327360);    // 192 ints
    float* outp     = (float*)d_out;

    prep_kernel<<<384, 384, 0, stream>>>(emb, tpin, fWih, fbih, alp, anch, npred, skern,
                                         aWih, aWhh, abih, abhh,
                                         xW, members, lens, abn_res);
    gru_feat_kernel<<<NANCH, 512, 0, stream>>>(xW, fWhh, fbhh, members, lens, anch, feat);
    head_kernel<<<NANCH, 256, 0, stream>>>(feat, abn_res, anch, alp,
                                           W1, b1, W2, b2, W3, b3, sw, ew, outp);
}

// Round 8
// 317.217 us; speedup vs baseline: 1.0111x; 1.0111x over previous
//
#include <hip/hip_runtime.h>
#include <math.h>

#define N_NODES 512
#define DIM 128
#define NANCH 192
#define G3 384           // 3*DIM gate width
#define FOUT 47
#define DBINS 21
#define WPAD 132         // 33 chunks/row: stride ≡ 1 (mod 8) in 16B-chunk units

__device__ __forceinline__ float fast_sigmoid(float x) {
    return __builtin_amdgcn_rcpf(1.f + __expf(-x));
}
__device__ __forceinline__ float fast_tanh(float x) {
    return 1.f - 2.f * __builtin_amdgcn_rcpf(1.f + __expf(2.f * x));
}

// ============ Kernel 1: fused [xW GEMM | membership + abnormal + H=1 BiGRU] ============
// (byte-identical to R8)
__global__ __launch_bounds__(384) void prep_kernel(
    const float* __restrict__ emb, const float* __restrict__ tpin,
    const float* __restrict__ Wih, const float* __restrict__ bih,
    const float* __restrict__ alp, const float* __restrict__ anchors,
    const float* __restrict__ npred, const float* __restrict__ skern,
    const float* __restrict__ aWih, const float* __restrict__ aWhh,
    const float* __restrict__ abih, const float* __restrict__ abhh,
    float* __restrict__ xW, int* __restrict__ members,
    int* __restrict__ lens, float* __restrict__ abn_res)
{
    int blk = blockIdx.x;
    int tid = threadIdx.x;     // 0..383
    if (blk < 192) {
        int sd = blk >> 5;         // 0..5
        int ng = blk & 31;         // 0..31
        __shared__ __align__(16) float xs[16][DIM];
        for (int idx = tid; idx < 16 * DIM; idx += 384) {
            int m = idx >> 7, k = idx & 127;
            int node = ng * 16 + m;
            float tv = tpin[node];
            float freq = 10.f * (float)k / 127.f;
            xs[m][k] = emb[node * DIM + k] + 0.05f * __sinf(tv * freq);
        }
        __syncthreads();
        float acc[16];
        float b = bih[sd * G3 + tid];
        #pragma unroll
        for (int m = 0; m < 16; ++m) acc[m] = b;
        const float* wrow = Wih + ((size_t)sd * G3 + tid) * DIM;
        for (int k = 0; k < DIM; k += 4) {
            float4 w4 = *(const float4*)(wrow + k);
            #pragma unroll
            for (int m = 0; m < 16; ++m) {
                float4 xv = *(const float4*)&xs[m][k];   // wave-uniform b128 broadcast
                acc[m] = fmaf(w4.x, xv.x, acc[m]);
                acc[m] = fmaf(w4.y, xv.y, acc[m]);
                acc[m] = fmaf(w4.z, xv.z, acc[m]);
                acc[m] = fmaf(w4.w, xv.w, acc[m]);
            }
        }
        #pragma unroll
        for (int m = 0; m < 16; ++m)
            xW[((size_t)sd * N_NODES + ng * 16 + m) * G3 + tid] = acc[m];
    } else {
        int a = blk - 192;
        float al = alp[0];
        float s0 = anchors[a * 2 + 0];
        float e0 = anchors[a * 2 + 1];
        __shared__ int memloc[N_NODES];
        __shared__ float abn_lds[N_NODES];
        for (int node = tid; node < N_NODES; node += 384) {
            float sc[5];
            #pragma unroll
            for (int ch = 0; ch < 5; ++ch) {
                float acc = 0.f;
                #pragma unroll
                for (int k = 0; k < 5; ++k) {
                    int r = node + k - 2;
                    if (r >= 0 && r < N_NODES) acc += skern[k] * npred[r * 5 + ch];
                }
                sc[ch] = acc;
            }
            float m = sc[0];
            #pragma unroll
            for (int ch = 1; ch < 5; ++ch) m = fmaxf(m, sc[ch]);
            float sum = 0.f;
            #pragma unroll
            for (int ch = 0; ch < 5; ++ch) sum += __expf(sc[ch] - m);
            abn_lds[node] = __expf(sc[0] - m) / sum;
        }
        __syncthreads();
        if (tid < 64) {
            int lane = tid;
            int count = 0;
            for (int c = 0; c < N_NODES / 64; ++c) {
                int node = c * 64 + lane;
                float tp = tpin[node] * al;
                bool in = (tp >= s0) && (tp <= e0);
                unsigned long long m = __ballot(in);
                if (in) {
                    int pos = count + __popcll(m & ((1ull << lane) - 1ull));
                    members[a * N_NODES + pos] = node;
                    memloc[pos] = node;
                }
                count += __popcll(m);
            }
            if (lane == 0) lens[a] = count;
            int sc3 = a >> 6;
            float h = 0.f;
            if (lane < 2) {
                int sd = sc3 * 2 + lane;
                float wi0 = aWih[sd*3+0], wi1 = aWih[sd*3+1], wi2 = aWih[sd*3+2];
                float wh0 = aWhh[sd*3+0], wh1 = aWhh[sd*3+1], wh2 = aWhh[sd*3+2];
                float bi0 = abih[sd*3+0], bi1 = abih[sd*3+1], bi2 = abih[sd*3+2];
                float bh0 = abhh[sd*3+0], bh1 = abhh[sd*3+1], bh2 = abhh[sd*3+2];
                for (int t = 0; t < count; ++t) {
                    int idx = lane ? (count - 1 - t) : t;
                    float xv = abn_lds[memloc[idx]];
                    float r = fast_sigmoid(fmaf(wi0, xv, bi0) + fmaf(wh0, h, bh0));
                    float z = fast_sigmoid(fmaf(wi1, xv, bi1) + fmaf(wh1, h, bh1));
                    float nv = fast_tanh(fmaf(wi2, xv, bi2) + r * fmaf(wh2, h, bh2));
                    h = (1.f - z) * nv + z * h;
                }
            }
            float hb = __shfl(h, 1);
            if (lane == 0) abn_res[a] = 0.5f * (h + hb);
        }
    }
}

// ============ Kernel 2: H=128 GRU — R16: identical re-run of R15 (infra flake) ============
// R15 never executed (container failed twice — same flake signature as R3, whose kernel
// later ran fine unchanged). Kernel re-audited: LDS 137.7 KB (same as R14, which ran),
// swizzle store p=(q&1)+2*sh+8*(q>>1) is bijective over 0..31 (bit decomposition),
// read addr = staged addr, bank-group (j+2s+(q&1)) mod 8 is a permutation over each
// 8-lane group -> conflict-free. Resubmitting byte-identical to keep the swizzle as
// the isolated variable vs R14's 6.44M-conflict run.
__global__ __launch_bounds__(512) void gru_feat_kernel(
    const float* __restrict__ xW, const float* __restrict__ Whh,
    const float* __restrict__ bhh, const int* __restrict__ members,
    const int* __restrict__ lens, const float* __restrict__ anchors,
    float* __restrict__ feat_out)
{
    int bb = blockIdx.x;       // 0..191
    int t0 = threadIdx.x;      // 0..511
    int j  = t0 >> 2;          // 0..127 : owned h element
    int s  = t0 & 3;           // 0..3   : 32-wide K slice
    int sc  = bb >> 6;         // scale 0..2 (64 blocks per scale)
    int idx = bb & 63;
    int dir = idx & 1;
    int pr  = idx >> 1;        // pair rank 0..31
    int sd  = sc * 2 + dir;

    __shared__ __align__(16) float ldsW[2 * DIM * WPAD];   // wr rows 0..127, wz rows 128..255
    __shared__ __align__(16) float hbA[2][4][36];
    __shared__ __align__(16) float hbB[2][4][36];
    __shared__ int perm_l[64];

    // ---- rank this scale's 64 anchors by width desc (bijective) ----
    if (t0 < 64) {
        int aa = sc * 64 + t0;
        float w = anchors[2 * aa + 1] - anchors[2 * aa];
        int rank = 0;
        for (int q = 0; q < 64; ++q) {
            int aq = sc * 64 + q;
            float wq = anchors[2 * aq + 1] - anchors[2 * aq];
            rank += (wq > w) || (wq == w && q < t0);
        }
        perm_l[rank] = aa;
    }
    // ---- stage wr,wz into LDS with the chunk-interleave swizzle ----
    const float* wbase = Whh + (size_t)sd * G3 * DIM;
    for (int i = t0; i < 2 * DIM * 32; i += 512) {      // 8192 float4 chunks
        int row = i >> 5, l = i & 31;                   // logical chunk l = s*8+q
        int q = l & 7, sh = l >> 3;
        int p = (q & 1) + 2 * sh + 8 * (q >> 1);        // physical chunk
        *(float4*)&ldsW[row * WPAD + 4 * p] = *(const float4*)(wbase + row * DIM + 4 * l);
    }
    for (int i = t0; i < 2 * 4 * 36; i += 512) { ((float*)hbA)[i] = 0.f; ((float*)hbB)[i] = 0.f; }
    __syncthreads();

    int a0 = perm_l[2 * pr], a1 = perm_l[2 * pr + 1];

    float bhr = bhh[sd * G3 + j];
    float bhz = bhh[sd * G3 + DIM + j];
    float bhn = bhh[sd * G3 + 2 * DIM + j];

    const float* xWp = xW + (size_t)sd * N_NODES * G3;
    const int* memA = members + a0 * N_NODES;  int lenA = lens[a0];
    const int* memB = members + a1 * N_NODES;  int lenB = lens[a1];
    int T = lenA > lenB ? lenA : lenB;

    // step-0 gi prefetch per anchor
    int n0A = (lenA > 0) ? memA[dir ? (lenA - 1) : 0] : 0;
    float grA = xWp[(size_t)n0A * G3 + j];
    float gzA = xWp[(size_t)n0A * G3 + DIM + j];
    float gnA = xWp[(size_t)n0A * G3 + 2 * DIM + j];
    int n0B = (lenB > 0) ? memB[dir ? (lenB - 1) : 0] : 0;
    float grB = xWp[(size_t)n0B * G3 + j];
    float gzB = xWp[(size_t)n0B * G3 + DIM + j];
    float gnB = xWp[(size_t)n0B * G3 + 2 * DIM + j];

    const float* wrb = &ldsW[(size_t)j * WPAD + 8 * s];            // swizzled base (gate r)
    const float* wzb = &ldsW[(size_t)(DIM + j) * WPAD + 8 * s];    // swizzled base (gate z)
    const float4* wnp = (const float4*)(wbase + (size_t)(2 * DIM + j) * DIM + s * 32);

    int cur = 0;
    for (int t = 0; t < T; ++t) {
        // wn stream for this step (8 dwordx4 from L2; issued first, consumed last)
        float4 wnv[8];
        #pragma unroll
        for (int q = 0; q < 8; ++q) wnv[q] = wnp[q];
        // next-step gi prefetch (overlaps compute + barrier)
        float grA_n = 0.f, gzA_n = 0.f, gnA_n = 0.f;
        float grB_n = 0.f, gzB_n = 0.f, gnB_n = 0.f;
        if (t + 1 < lenA) {
            int nn = memA[dir ? (lenA - 2 - t) : (t + 1)];
            grA_n = xWp[(size_t)nn * G3 + j];
            gzA_n = xWp[(size_t)nn * G3 + DIM + j];
            gnA_n = xWp[(size_t)nn * G3 + 2 * DIM + j];
        }
        if (t + 1 < lenB) {
            int nn = memB[dir ? (lenB - 2 - t) : (t + 1)];
            grB_n = xWp[(size_t)nn * G3 + j];
            gzB_n = xWp[(size_t)nn * G3 + DIM + j];
            gnB_n = xWp[(size_t)nn * G3 + 2 * DIM + j];
        }
        // partial dots: weights (LDS swizzled + streamed regs) x h (LDS broadcast)
        float arA = 0.f, azA = 0.f, anA = 0.f, arB = 0.f, azB = 0.f, anB = 0.f;
        const float4* hA4 = (const float4*)&hbA[cur][s][0];
        const float4* hB4 = (const float4*)&hbB[cur][s][0];
        #pragma unroll
        for (int q = 0; q < 8; ++q) {
            const int cq = 4 * (q & 1) + 32 * (q >> 1);   // compile-time swizzled offset
            float4 wv = *(const float4*)&wrb[cq];
            float4 zv = *(const float4*)&wzb[cq];
            float4 nv = wnv[q];
            float4 ha = hA4[q], hb = hB4[q];
            arA = fmaf(wv.x, ha.x, arA); arA = fmaf(wv.y, ha.y, arA);
            arA = fmaf(wv.z, ha.z, arA); arA = fmaf(wv.w, ha.w, arA);
            azA = fmaf(zv.x, ha.x, azA); azA = fmaf(zv.y, ha.y, azA);
            azA = fmaf(zv.z, ha.z, azA); azA = fmaf(zv.w, ha.w, azA);
            anA = fmaf(nv.x, ha.x, anA); anA = fmaf(nv.y, ha.y, anA);
            anA = fmaf(nv.z, ha.z, anA); anA = fmaf(nv.w, ha.w, anA);
            arB = fmaf(wv.x, hb.x, arB); arB = fmaf(wv.y, hb.y, arB);
            arB = fmaf(wv.z, hb.z, arB); arB = fmaf(wv.w, hb.w, arB);
            azB = fmaf(zv.x, hb.x, azB); azB = fmaf(zv.y, hb.y, azB);
            azB = fmaf(zv.z, hb.z, azB); azB = fmaf(zv.w, hb.w, azB);
            anB = fmaf(nv.x, hb.x, anB); anB = fmaf(nv.y, hb.y, anB);
            anB = fmaf(nv.z, hb.z, anB); anB = fmaf(nv.w, hb.w, anB);
        }
        // quad reduction (lanes 4j..4j+3 adjacent in wave)
        arA += __shfl_xor(arA, 1); arA += __shfl_xor(arA, 2);
        azA += __shfl_xor(azA, 1); azA += __shfl_xor(azA, 2);
        anA += __shfl_xor(anA, 1); anA += __shfl_xor(anA, 2);
        arB += __shfl_xor(arB, 1); arB += __shfl_xor(arB, 2);
        azB += __shfl_xor(azB, 1); azB += __shfl_xor(azB, 2);
        anB += __shfl_xor(anB, 1); anB += __shfl_xor(anB, 2);

        float rA = fast_sigmoid(grA + arA + bhr);
        float zA = fast_sigmoid(gzA + azA + bhz);
        float nA = fast_tanh(gnA + rA * (anA + bhn));
        float hjA = hbA[cur][j >> 5][j & 31];
        float hnA = (t < lenA) ? ((1.f - zA) * nA + zA * hjA) : hjA;  // copy-through after lenA

        float rB = fast_sigmoid(grB + arB + bhr);
        float zB = fast_sigmoid(gzB + azB + bhz);
        float nB = fast_tanh(gnB + rB * (anB + bhn));
        float hjB = hbB[cur][j >> 5][j & 31];
        float hnB = (t < lenB) ? ((1.f - zB) * nB + zB * hjB) : hjB;

        if (s == 0) {
            hbA[cur ^ 1][j >> 5][j & 31] = hnA;
            hbB[cur ^ 1][j >> 5][j & 31] = hnB;
        }
        __syncthreads();
        cur ^= 1;
        grA = grA_n; gzA = gzA_n; gnA = gnA_n;
        grB = grB_n; gzB = gzB_n; gnB = gnB_n;
    }
    if (s == 0) {
        feat_out[a0 * 256 + dir * DIM + j] = hbA[cur][j >> 5][j & 31];
        feat_out[a1 * 256 + dir * DIM + j] = hbB[cur][j >> 5][j & 31];
    }
}

// ============ Kernel 3: per-anchor MLP head + boundary refinement ============
// (byte-identical to R8)
__global__ __launch_bounds__(256) void head_kernel(
    const float* __restrict__ feat, const float* __restrict__ abn_res,
    const float* __restrict__ anchors, const float* __restrict__ alp,
    const float* __restrict__ W1, const float* __restrict__ b1,
    const float* __restrict__ W2, const float* __restrict__ b2,
    const float* __restrict__ W3, const float* __restrict__ b3,
    const float* __restrict__ sw, const float* __restrict__ ew,
    float* __restrict__ out)
{
    int a = blockIdx.x;
    int tid = threadIdx.x;   // 0..255
    int s = a >> 6;
    __shared__ float sf[260];
    __shared__ float h1[256];
    __shared__ float h2[256];
    __shared__ float o[FOUT];
    float al = alp[0];
    float st = anchors[a * 2 + 0];
    float en = anchors[a * 2 + 1];
    sf[tid] = feat[a * 256 + tid];
    if (tid == 0) {
        sf[256] = abn_res[a];
        sf[257] = (st + en) * 0.5f / al;
        sf[258] = (en - st) / al;
    }
    __syncthreads();

    const float* w1 = W1 + (size_t)s * 259 * 256;
    float acc = b1[s * 256 + tid];
    for (int jj = 0; jj < 259; ++jj) acc = fmaf(sf[jj], w1[jj * 256 + tid], acc);
    h1[tid] = fmaxf(acc, 0.f);
    __syncthreads();

    const float* w2 = W2 + (size_t)s * 256 * 256;
    acc = b2[s * 256 + tid];
    for (int jj = 0; jj < 256; ++jj) acc = fmaf(h1[jj], w2[jj * 256 + tid], acc);
    h2[tid] = fmaxf(acc, 0.f);
    __syncthreads();

    if (tid < FOUT) {
        const float* w3 = W3 + (size_t)s * 256 * FOUT;
        acc = b3[s * FOUT + tid];
        for (int jj = 0; jj < 256; ++jj) acc = fmaf(h2[jj], w3[jj * FOUT + tid], acc);
        o[tid] = acc;
    }
    __syncthreads();

    if (tid < 2) {   // tid 0: start offset, tid 1: end offset
        const float* lw = (tid == 0) ? (sw + s * DBINS) : (ew + s * DBINS);
        const float* sl = o + tid * DBINS;
        float m = sl[0];
        for (int jj = 1; jj < DBINS; ++jj) m = fmaxf(m, sl[jj]);
        float sum = 0.f, dot = 0.f;
        for (int jj = 0; jj < DBINS; ++jj) {
            float e = __expf(sl[jj] - m);
            sum += e;
            dot = fmaf(e, lw[jj], dot);
        }
        float off = dot / sum;
        float base = (tid == 0) ? st : en;
        out[a * 2 + tid] = fminf(fmaxf(base + off, 0.f), al);
    }
    if (tid == 42) out[2 * NANCH + a] = o[42];                           // conf
    if (tid >= 43 && tid < FOUT) out[3 * NANCH + a * 4 + (tid - 43)] = o[tid]; // cls
}

extern "C" void kernel_launch(void* const* d_in, const int* in_sizes, int n_in,
                              void* d_out, int out_size, void* d_ws, size_t ws_size,
                              hipStream_t stream) {
    const float* emb   = (const float*)d_in[0];
    const float* tpin  = (const float*)d_in[1];
    const float* npred = (const float*)d_in[2];
    const float* alp   = (const float*)d_in[3];
    const float* anch  = (const float*)d_in[4];
    const float* skern = (const float*)d_in[5];
    const float* fWih  = (const float*)d_in[6];
    const float* fWhh  = (const float*)d_in[7];
    const float* fbih  = (const float*)d_in[8];
    const float* fbhh  = (const float*)d_in[9];
    const float* aWih  = (const float*)d_in[10];
    const float* aWhh  = (const float*)d_in[11];
    const float* abih  = (const float*)d_in[12];
    const float* abhh  = (const float*)d_in[13];
    const float* sw    = (const float*)d_in[14];
    const float* ew    = (const float*)d_in[15];
    const float* W1    = (const float*)d_in[16];
    const float* b1    = (const float*)d_in[17];
    const float* W2    = (const float*)d_in[18];
    const float* b2    = (const float*)d_in[19];
    const float* W3    = (const float*)d_in[20];
    const float* b3    = (const float*)d_in[21];

    float* ws = (float*)d_ws;
    float* xW       = ws;                      // 6*512*384 = 1179648
    float* abn_res  = ws + 1179648;            // 192 (pad 256)
    float* feat     = ws + 1179904;            // 192*256 = 49152
    int*   members  = (int*)(ws + 1229056);    // 192*512 ints = 98304
    int*   lens     = (int*)(ws + 1327360);    // 192 ints
    float* outp     = (float*)d_out;

    prep_kernel<<<384, 384, 0, stream>>>(emb, tpin, fWih, fbih, alp, anch, npred, skern,
                                         aWih, aWhh, abih, abhh,
                                         xW, members, lens, abn_res);
    gru_feat_kernel<<<NANCH, 512, 0, stream>>>(xW, fWhh, fbhh, members, lens, anch, feat);
    head_kernel<<<NANCH, 256, 0, stream>>>(feat, abn_res, anch, alp,
                                           W1, b1, W2, b2, W3, b3, sw, ew, outp);
}

// Round 9
// 286.507 us; speedup vs baseline: 1.1195x; 1.1072x over previous
//
#include <hip/hip_runtime.h>
#include <math.h>

#define N_NODES 512
#define DIM 128
#define NANCH 192
#define G3 384           // 3*DIM gate width
#define FOUT 47
#define DBINS 21

__device__ __forceinline__ float fast_sigmoid(float x) {
    return __builtin_amdgcn_rcpf(1.f + __expf(-x));
}
__device__ __forceinline__ float fast_tanh(float x) {
    return 1.f - 2.f * __builtin_amdgcn_rcpf(1.f + __expf(2.f * x));
}

// ============ Kernel 1: fused [xW GEMM | membership + abnormal + H=1 BiGRU] ============
// (byte-identical to R8)
__global__ __launch_bounds__(384) void prep_kernel(
    const float* __restrict__ emb, const float* __restrict__ tpin,
    const float* __restrict__ Wih, const float* __restrict__ bih,
    const float* __restrict__ alp, const float* __restrict__ anchors,
    const float* __restrict__ npred, const float* __restrict__ skern,
    const float* __restrict__ aWih, const float* __restrict__ aWhh,
    const float* __restrict__ abih, const float* __restrict__ abhh,
    float* __restrict__ xW, int* __restrict__ members,
    int* __restrict__ lens, float* __restrict__ abn_res)
{
    int blk = blockIdx.x;
    int tid = threadIdx.x;     // 0..383
    if (blk < 192) {
        int sd = blk >> 5;         // 0..5
        int ng = blk & 31;         // 0..31
        __shared__ __align__(16) float xs[16][DIM];
        for (int idx = tid; idx < 16 * DIM; idx += 384) {
            int m = idx >> 7, k = idx & 127;
            int node = ng * 16 + m;
            float tv = tpin[node];
            float freq = 10.f * (float)k / 127.f;
            xs[m][k] = emb[node * DIM + k] + 0.05f * __sinf(tv * freq);
        }
        __syncthreads();
        float acc[16];
        float b = bih[sd * G3 + tid];
        #pragma unroll
        for (int m = 0; m < 16; ++m) acc[m] = b;
        const float* wrow = Wih + ((size_t)sd * G3 + tid) * DIM;
        for (int k = 0; k < DIM; k += 4) {
            float4 w4 = *(const float4*)(wrow + k);
            #pragma unroll
            for (int m = 0; m < 16; ++m) {
                float4 xv = *(const float4*)&xs[m][k];   // wave-uniform b128 broadcast
                acc[m] = fmaf(w4.x, xv.x, acc[m]);
                acc[m] = fmaf(w4.y, xv.y, acc[m]);
                acc[m] = fmaf(w4.z, xv.z, acc[m]);
                acc[m] = fmaf(w4.w, xv.w, acc[m]);
            }
        }
        #pragma unroll
        for (int m = 0; m < 16; ++m)
            xW[((size_t)sd * N_NODES + ng * 16 + m) * G3 + tid] = acc[m];
    } else {
        int a = blk - 192;
        float al = alp[0];
        float s0 = anchors[a * 2 + 0];
        float e0 = anchors[a * 2 + 1];
        __shared__ int memloc[N_NODES];
        __shared__ float abn_lds[N_NODES];
        for (int node = tid; node < N_NODES; node += 384) {
            float sc[5];
            #pragma unroll
            for (int ch = 0; ch < 5; ++ch) {
                float acc = 0.f;
                #pragma unroll
                for (int k = 0; k < 5; ++k) {
                    int r = node + k - 2;
                    if (r >= 0 && r < N_NODES) acc += skern[k] * npred[r * 5 + ch];
                }
                sc[ch] = acc;
            }
            float m = sc[0];
            #pragma unroll
            for (int ch = 1; ch < 5; ++ch) m = fmaxf(m, sc[ch]);
            float sum = 0.f;
            #pragma unroll
            for (int ch = 0; ch < 5; ++ch) sum += __expf(sc[ch] - m);
            abn_lds[node] = __expf(sc[0] - m) / sum;
        }
        __syncthreads();
        if (tid < 64) {
            int lane = tid;
            int count = 0;
            for (int c = 0; c < N_NODES / 64; ++c) {
                int node = c * 64 + lane;
                float tp = tpin[node] * al;
                bool in = (tp >= s0) && (tp <= e0);
                unsigned long long m = __ballot(in);
                if (in) {
                    int pos = count + __popcll(m & ((1ull << lane) - 1ull));
                    members[a * N_NODES + pos] = node;
                    memloc[pos] = node;
                }
                count += __popcll(m);
            }
            if (lane == 0) lens[a] = count;
            int sc3 = a >> 6;
            float h = 0.f;
            if (lane < 2) {
                int sd = sc3 * 2 + lane;
                float wi0 = aWih[sd*3+0], wi1 = aWih[sd*3+1], wi2 = aWih[sd*3+2];
                float wh0 = aWhh[sd*3+0], wh1 = aWhh[sd*3+1], wh2 = aWhh[sd*3+2];
                float bi0 = abih[sd*3+0], bi1 = abih[sd*3+1], bi2 = abih[sd*3+2];
                float bh0 = abhh[sd*3+0], bh1 = abhh[sd*3+1], bh2 = abhh[sd*3+2];
                for (int t = 0; t < count; ++t) {
                    int idx = lane ? (count - 1 - t) : t;
                    float xv = abn_lds[memloc[idx]];
                    float r = fast_sigmoid(fmaf(wi0, xv, bi0) + fmaf(wh0, h, bh0));
                    float z = fast_sigmoid(fmaf(wi1, xv, bi1) + fmaf(wh1, h, bh1));
                    float nv = fast_tanh(fmaf(wi2, xv, bi2) + r * fmaf(wh2, h, bh2));
                    h = (1.f - z) * nv + z * h;
                }
            }
            float hb = __shfl(h, 1);
            if (lane == 0) abn_res[a] = 0.5f * (h + hb);
        }
    }
}

// ============ Kernel 2: H=128 GRU — R17: paired anchors sharing one L2 weight stream ============
// R14/R16 post-mortem: LDS-weights dead (swizzle didn't reduce the ~7M conflicts;
// b128 weight reads at this shape are intrinsically expensive). R8's real limit:
// 196KB/block/step Whh stream -> implied ~26TB/s chip L2 traffic, right at the
// 34.5TB/s ceiling (VALUBusy 51%, step 2200cyc vs ~620 issue). This round HALVES
// bytes per anchor-step with zero new storage: each block serves TWO anchors of the
// same (scale,dir); the 24 in-loop float4 weight loads feed 6 FMAs each (A and B).
// The compiler's refusal to hoist loop-invariant loads (proven R9-R13) keeps the
// loads streaming in-loop at 8-wave occupancy — now by design. 192 blocks <= 256 CUs:
// every pair resident from t=0, makespan = len_max (~102 steps). Inner arithmetic
// per anchor is bit-identical to R8 (same slicing, same shuffle order) -> absmax 0.
__global__ __launch_bounds__(512) void gru_feat_kernel(
    const float* __restrict__ xW, const float* __restrict__ Whh,
    const float* __restrict__ bhh, const int* __restrict__ members,
    const int* __restrict__ lens, const float* __restrict__ anchors,
    float* __restrict__ feat_out)
{
    int bb = blockIdx.x;       // 0..191
    int t0 = threadIdx.x;      // 0..511
    int j  = t0 >> 2;          // 0..127 : owned h element
    int s  = t0 & 3;           // 0..3   : 32-wide K slice
    int sc  = bb >> 6;         // scale 0..2
    int idx = bb & 63;
    int dir = idx & 1;
    int pr  = idx >> 1;        // pair rank 0..31
    int sd  = sc * 2 + dir;

    __shared__ int perm_l[64];
    __shared__ __align__(16) float hbA[2][4][36];
    __shared__ __align__(16) float hbB[2][4][36];

    // ---- rank this scale's 64 anchors by width desc (bijective; width ~ len proxy) ----
    if (t0 < 64) {
        int aa = sc * 64 + t0;
        float w = anchors[2 * aa + 1] - anchors[2 * aa];
        int rank = 0;
        for (int q = 0; q < 64; ++q) {
            int aq = sc * 64 + q;
            float wq = anchors[2 * aq + 1] - anchors[2 * aq];
            rank += (wq > w) || (wq == w && q < t0);
        }
        perm_l[rank] = aa;
    }
    for (int i = t0; i < 2 * 4 * 36; i += 512) { ((float*)hbA)[i] = 0.f; ((float*)hbB)[i] = 0.f; }
    __syncthreads();

    int a0 = perm_l[2 * pr], a1 = perm_l[2 * pr + 1];

    float bhr = bhh[sd * G3 + j];
    float bhz = bhh[sd * G3 + DIM + j];
    float bhn = bhh[sd * G3 + 2 * DIM + j];

    const float* wbase = Whh + (size_t)sd * G3 * DIM;
    const float4* wr4 = (const float4*)(wbase + (size_t)(j        ) * DIM + s * 32);
    const float4* wz4 = (const float4*)(wbase + (size_t)(j + DIM  ) * DIM + s * 32);
    const float4* wn4 = (const float4*)(wbase + (size_t)(j + 2*DIM) * DIM + s * 32);

    const float* xWp = xW + (size_t)sd * N_NODES * G3;
    const int* memA = members + a0 * N_NODES;  int lenA = lens[a0];
    const int* memB = members + a1 * N_NODES;  int lenB = lens[a1];
    int T = lenA > lenB ? lenA : lenB;

    // step-0 gi prefetch per anchor
    int n0A = (lenA > 0) ? memA[dir ? (lenA - 1) : 0] : 0;
    float grA = xWp[(size_t)n0A * G3 + j];
    float gzA = xWp[(size_t)n0A * G3 + DIM + j];
    float gnA = xWp[(size_t)n0A * G3 + 2 * DIM + j];
    int n0B = (lenB > 0) ? memB[dir ? (lenB - 1) : 0] : 0;
    float grB = xWp[(size_t)n0B * G3 + j];
    float gzB = xWp[(size_t)n0B * G3 + DIM + j];
    float gnB = xWp[(size_t)n0B * G3 + 2 * DIM + j];

    int cur = 0;
    for (int t = 0; t < T; ++t) {
        // next-step gi prefetch (overlaps compute + barrier)
        float grA_n = 0.f, gzA_n = 0.f, gnA_n = 0.f;
        float grB_n = 0.f, gzB_n = 0.f, gnB_n = 0.f;
        if (t + 1 < lenA) {
            int nn = memA[dir ? (lenA - 2 - t) : (t + 1)];
            grA_n = xWp[(size_t)nn * G3 + j];
            gzA_n = xWp[(size_t)nn * G3 + DIM + j];
            gnA_n = xWp[(size_t)nn * G3 + 2 * DIM + j];
        }
        if (t + 1 < lenB) {
            int nn = memB[dir ? (lenB - 2 - t) : (t + 1)];
            grB_n = xWp[(size_t)nn * G3 + j];
            gzB_n = xWp[(size_t)nn * G3 + DIM + j];
            gnB_n = xWp[(size_t)nn * G3 + 2 * DIM + j];
        }
        // partial dots: ONE weight stream (24 float4 loads) feeds BOTH anchors
        float arA = 0.f, azA = 0.f, anA = 0.f, arB = 0.f, azB = 0.f, anB = 0.f;
        const float4* hA4 = (const float4*)&hbA[cur][s][0];
        const float4* hB4 = (const float4*)&hbB[cur][s][0];
        #pragma unroll
        for (int q = 0; q < 8; ++q) {
            float4 wv = wr4[q];
            float4 zv = wz4[q];
            float4 nv = wn4[q];
            float4 ha = hA4[q], hb = hB4[q];
            arA = fmaf(wv.x, ha.x, arA); arA = fmaf(wv.y, ha.y, arA);
            arA = fmaf(wv.z, ha.z, arA); arA = fmaf(wv.w, ha.w, arA);
            azA = fmaf(zv.x, ha.x, azA); azA = fmaf(zv.y, ha.y, azA);
            azA = fmaf(zv.z, ha.z, azA); azA = fmaf(zv.w, ha.w, azA);
            anA = fmaf(nv.x, ha.x, anA); anA = fmaf(nv.y, ha.y, anA);
            anA = fmaf(nv.z, ha.z, anA); anA = fmaf(nv.w, ha.w, anA);
            arB = fmaf(wv.x, hb.x, arB); arB = fmaf(wv.y, hb.y, arB);
            arB = fmaf(wv.z, hb.z, arB); arB = fmaf(wv.w, hb.w, arB);
            azB = fmaf(zv.x, hb.x, azB); azB = fmaf(zv.y, hb.y, azB);
            azB = fmaf(zv.z, hb.z, azB); azB = fmaf(zv.w, hb.w, azB);
            anB = fmaf(nv.x, hb.x, anB); anB = fmaf(nv.y, hb.y, anB);
            anB = fmaf(nv.z, hb.z, anB); anB = fmaf(nv.w, hb.w, anB);
        }
        // quad reduction (lanes 4j..4j+3 adjacent in wave)
        arA += __shfl_xor(arA, 1); arA += __shfl_xor(arA, 2);
        azA += __shfl_xor(azA, 1); azA += __shfl_xor(azA, 2);
        anA += __shfl_xor(anA, 1); anA += __shfl_xor(anA, 2);
        arB += __shfl_xor(arB, 1); arB += __shfl_xor(arB, 2);
        azB += __shfl_xor(azB, 1); azB += __shfl_xor(azB, 2);
        anB += __shfl_xor(anB, 1); anB += __shfl_xor(anB, 2);

        float rA = fast_sigmoid(grA + arA + bhr);
        float zA = fast_sigmoid(gzA + azA + bhz);
        float nA = fast_tanh(gnA + rA * (anA + bhn));
        float hjA = hbA[cur][j >> 5][j & 31];
        float hnA = (t < lenA) ? ((1.f - zA) * nA + zA * hjA) : hjA;  // copy-through after lenA

        float rB = fast_sigmoid(grB + arB + bhr);
        float zB = fast_sigmoid(gzB + azB + bhz);
        float nB = fast_tanh(gnB + rB * (anB + bhn));
        float hjB = hbB[cur][j >> 5][j & 31];
        float hnB = (t < lenB) ? ((1.f - zB) * nB + zB * hjB) : hjB;

        if (s == 0) {
            hbA[cur ^ 1][j >> 5][j & 31] = hnA;
            hbB[cur ^ 1][j >> 5][j & 31] = hnB;
        }
        __syncthreads();
        cur ^= 1;
        grA = grA_n; gzA = gzA_n; gnA = gnA_n;
        grB = grB_n; gzB = gzB_n; gnB = gnB_n;
    }
    if (s == 0) {
        feat_out[a0 * 256 + dir * DIM + j] = hbA[cur][j >> 5][j & 31];
        feat_out[a1 * 256 + dir * DIM + j] = hbB[cur][j >> 5][j & 31];
    }
}

// ============ Kernel 3: per-anchor MLP head + boundary refinement ============
// (byte-identical to R8)
__global__ __launch_bounds__(256) void head_kernel(
    const float* __restrict__ feat, const float* __restrict__ abn_res,
    const float* __restrict__ anchors, const float* __restrict__ alp,
    const float* __restrict__ W1, const float* __restrict__ b1,
    const float* __restrict__ W2, const float* __restrict__ b2,
    const float* __restrict__ W3, const float* __restrict__ b3,
    const float* __restrict__ sw, const float* __restrict__ ew,
    float* __restrict__ out)
{
    int a = blockIdx.x;
    int tid = threadIdx.x;   // 0..255
    int s = a >> 6;
    __shared__ float sf[260];
    __shared__ float h1[256];
    __shared__ float h2[256];
    __shared__ float o[FOUT];
    float al = alp[0];
    float st = anchors[a * 2 + 0];
    float en = anchors[a * 2 + 1];
    sf[tid] = feat[a * 256 + tid];
    if (tid == 0) {
        sf[256] = abn_res[a];
        sf[257] = (st + en) * 0.5f / al;
        sf[258] = (en - st) / al;
    }
    __syncthreads();

    const float* w1 = W1 + (size_t)s * 259 * 256;
    float acc = b1[s * 256 + tid];
    for (int jj = 0; jj < 259; ++jj) acc = fmaf(sf[jj], w1[jj * 256 + tid], acc);
    h1[tid] = fmaxf(acc, 0.f);
    __syncthreads();

    const float* w2 = W2 + (size_t)s * 256 * 256;
    acc = b2[s * 256 + tid];
    for (int jj = 0; jj < 256; ++jj) acc = fmaf(h1[jj], w2[jj * 256 + tid], acc);
    h2[tid] = fmaxf(acc, 0.f);
    __syncthreads();

    if (tid < FOUT) {
        const float* w3 = W3 + (size_t)s * 256 * FOUT;
        acc = b3[s * FOUT + tid];
        for (int jj = 0; jj < 256; ++jj) acc = fmaf(h2[jj], w3[jj * FOUT + tid], acc);
        o[tid] = acc;
    }
    __syncthreads();

    if (tid < 2) {   // tid 0: start offset, tid 1: end offset
        const float* lw = (tid == 0) ? (sw + s * DBINS) : (ew + s * DBINS);
        const float* sl = o + tid * DBINS;
        float m = sl[0];
        for (int jj = 1; jj < DBINS; ++jj) m = fmaxf(m, sl[jj]);
        float sum = 0.f, dot = 0.f;
        for (int jj = 0; jj < DBINS; ++jj) {
            float e = __expf(sl[jj] - m);
            sum += e;
            dot = fmaf(e, lw[jj], dot);
        }
        float off = dot / sum;
        float base = (tid == 0) ? st : en;
        out[a * 2 + tid] = fminf(fmaxf(base + off, 0.f), al);
    }
    if (tid == 42) out[2 * NANCH + a] = o[42];                           // conf
    if (tid >= 43 && tid < FOUT) out[3 * NANCH + a * 4 + (tid - 43)] = o[tid]; // cls
}

extern "C" void kernel_launch(void* const* d_in, const int* in_sizes, int n_in,
                              void* d_out, int out_size, void* d_ws, size_t ws_size,
                              hipStream_t stream) {
    const float* emb   = (const float*)d_in[0];
    const float* tpin  = (const float*)d_in[1];
    const float* npred = (const float*)d_in[2];
    const float* alp   = (const float*)d_in[3];
    const float* anch  = (const float*)d_in[4];
    const float* skern = (const float*)d_in[5];
    const float* fWih  = (const float*)d_in[6];
    const float* fWhh  = (const float*)d_in[7];
    const float* fbih  = (const float*)d_in[8];
    const float* fbhh  = (const float*)d_in[9];
    const float* aWih  = (const float*)d_in[10];
    const float* aWhh  = (const float*)d_in[11];
    const float* abih  = (const float*)d_in[12];
    const float* abhh  = (const float*)d_in[13];
    const float* sw    = (const float*)d_in[14];
    const float* ew    = (const float*)d_in[15];
    const float* W1    = (const float*)d_in[16];
    const float* b1    = (const float*)d_in[17];
    const float* W2    = (const float*)d_in[18];
    const float* b2    = (const float*)d_in[19];
    const float* W3    = (const float*)d_in[20];
    const float* b3    = (const float*)d_in[21];

    float* ws = (float*)d_ws;
    float* xW       = ws;                      // 6*512*384 = 1179648
    float* abn_res  = ws + 1179648;            // 192 (pad 256)
    float* feat     = ws + 1179904;            // 192*256 = 49152
    int*   members  = (int*)(ws + 1229056);    // 192*512 ints = 98304
    int*   lens     = (int*)(ws + 1327360);    // 192 ints
    float* outp     = (float*)d_out;

    prep_kernel<<<384, 384, 0, stream>>>(emb, tpin, fWih, fbih, alp, anch, npred, skern,
                                         aWih, aWhh, abih, abhh,
                                         xW, members, lens, abn_res);
    gru_feat_kernel<<<NANCH, 512, 0, stream>>>(xW, fWhh, fbhh, members, lens, anch, feat);
    head_kernel<<<NANCH, 256, 0, stream>>>(feat, abn_res, anch, alp,
                                           W1, b1, W2, b2, W3, b3, sw, ew, outp);
}